// Round 18
// baseline (54.213 us; speedup 1.0000x reference)
//
#include <hip/hip_runtime.h>
#include <math.h>

constexpr int Bc = 64;      // batch
constexpr int Vc = 8000;    // vocab
constexpr int Kc = 50;      // topics

// ws float-offsets
#define WS_NSUM   0        // 50  exp_n colsum (atomic)
#define WS_SSUM   50       // 50  exp_s colsum (atomic)
#define WS_BATCHC 151      // batch_C (atomic int)
#define WS_SCNT   152      // seed-word count (atomic int)
#define WS_QZSH   160      // 32 qz shards -> 192
#define WS_PM     256      // 32 shards x 3200 -> 102656 (zeroed by k1 spare blocks)
#define WS_GSRSH  102656   // 64*50 gamma_sr_sum shards -> 105856
#define WS_SSNSH  105856   // 32*50 exp_s_sum_new shards -> 107456
#define WS_ZEND   107456   // end of accumulator region
#define WS_TH     107456   // 3200 theta[b][k] -> 110656
#define WS_SW     110656   // 8000 seed-word flags -> 118656
#define WS_END    118656   // 474 KB

// fallback-only small offsets
#define FB_QZ     150
#define FB_GSR    200      // 50
#define FB_SSN    256      // 50

// ---------------- k1: colsums, batchC, flags, theta + PM-region zeroing ------
__global__ __launch_bounds__(256) void k1_pre(const int* __restrict__ bow,
    const float* __restrict__ seeds, const float* __restrict__ exp_n,
    const float* __restrict__ exp_s, const int* __restrict__ bidx,
    const float* __restrict__ exp_m, float* __restrict__ ws)
{
    const int t = threadIdx.x, blk = blockIdx.x;
    if (blk < 100) {
        __shared__ float csn[Kc], css[Kc];
        if (t < Kc) { csn[t] = 0.f; css[t] = 0.f; }
        __syncthreads();
        const int l = t & 63, w = t >> 6;
        const int q = (blk >> 1)*64 + l;     // 0..3199
        const int k = q % 50;
        float sn = 0.f, ss = 0.f;
        for (int j = w + (blk & 1)*4; j < 125; j += 8) {
            int flat = j*3200 + q;           // coalesced
            sn += exp_n[flat];
            ss += exp_s[flat];
        }
        atomicAdd(&csn[k], sn);
        atomicAdd(&css[k], ss);
        __syncthreads();
        if (t < Kc) {
            atomicAdd(&ws[WS_NSUM + t], csn[t]);
            atomicAdd(&ws[WS_SSUM + t], css[t]);
        }
    } else if (blk < 164) {
        const int4* b4 = (const int4*)bow;
        int acc = 0;
        for (int i = (blk-100)*256 + t; i < Bc*Vc/4; i += 64*256) {
            int4 x = b4[i];
            acc += x.x + x.y + x.z + x.w;
        }
        for (int off = 32; off; off >>= 1) acc += __shfl_xor(acc, off);
        __shared__ int ri[4];
        if ((t & 63) == 0) ri[t >> 6] = acc;
        __syncthreads();
        if (t == 0) atomicAdd((int*)ws + WS_BATCHC, ri[0]+ri[1]+ri[2]+ri[3]);
    } else if (blk < 196) {
        int v = (blk-164)*256 + t;
        int any = 0;
        if (v < Vc) {
            const float2* rp = (const float2*)(seeds + v*Kc);
            for (int j = 0; j < 25; ++j) {
                float2 x = rp[j];
                any |= (x.x != 0.f) | (x.y != 0.f);
            }
            ws[WS_SW + v] = any ? 1.f : 0.f;
        }
        unsigned long long m = __ballot(any);
        if ((t & 63) == 0) atomicAdd((int*)ws + WS_SCNT, (int)__popcll(m));
    } else if (blk < 197) {
        for (int i = t; i < Bc*Kc; i += 256) {
            int b = i / Kc, k = i - b*Kc;
            ws[WS_TH + i] = exp_m[bidx[b]*Kc + k] + 0.1f;
        }
    } else {
        // zero the big accumulator region [256, WS_ZEND) (47 blocks).
        // Race-free: k1's own atomics only touch [0,256); kF (stream-ordered
        // after k1) is the only writer of this region.
        int base = 256 + (blk - 197)*2304 + t;
#pragma unroll
        for (int j = 0; j < 9; ++j) {
            int idx = base + j*256;
            if (idx < WS_ZEND) ws[idx] = 0.f;
        }
    }
}

// ---------------- kF: fused middle + final n/s write -------------------------
// r17 body with ONE change: v-tile 16 -> 8 (grid 1008, LDS 38KB -> 4 blocks/CU,
// work-waves/CU 7.9 -> 15.75). Wave structure identical (2 v/wave, jj unroll 2,
// theta from LDS, pm[50] regs static-idx, sequential pm merge, log2-domain qz).
__global__ __launch_bounds__(256) void kF(const int* __restrict__ bow,
    const float* __restrict__ seeds, const float* __restrict__ exp_n,
    const float* __restrict__ exp_s, const float* __restrict__ pi,
    const int* __restrict__ itern_p, float* __restrict__ ws,
    float* __restrict__ out)
{
    const int id = blockIdx.x;
    const int vt = (id & 7)*126 + (id >> 3);  // XCD-pinned v-tile (8 v)
    if (vt >= Vc/8) return;                   // 1000 tiles, 1008 blocks
    const int v0 = vt * 8;

    __shared__ float  th_l[64*51];       // 13056 B  theta [b][k] stride 51
    __shared__ float  pmb[64*51];        // 13056 B  pm accum [b][k] stride 51
    __shared__ float2 cd_l[8*50];        //  3200 B  (C,D)
    __shared__ float2 gg_l[8*50];        //  3200 B  (GE,GF)
    __shared__ float  n1_l[8*50];        //  1600 B
    __shared__ float2 ii_l[8*64];        //  4096 B  (is, ir)
    __shared__ unsigned short bow_l[8*64]; // 1024 B
    __shared__ float  den_l[152];        // invS|invR|pi
    __shared__ float  sw_l[8];
    __shared__ float  qz_l;

    const int t = threadIdx.x, lane = t & 63, w = t >> 6;

    int ii = itern_p[0];
    float itern = (ii >= 0 && ii < 1000000) ? (float)ii : __int_as_float(ii);
    const float rho = 1.f / powf(itern + 5.f, 0.9f);
    const float omr = 1.f - rho;

    // ---- staging ----
    for (int i = t; i < Bc*Kc; i += 256) {
        int b = i / 50, k = i - b*50;
        th_l[b*51 + k] = ws[WS_TH + i];
        pmb[b*51 + k]  = 0.f;
    }
    if (t < 50) {
        float Sf = (float)(((const int*)ws)[WS_SCNT]);
        den_l[t] = 1.f / (0.1f*Sf + ws[WS_SSUM + t]);
    } else if (t < 100) {
        den_l[t] = 1.f / (0.1f*(float)Vc + ws[WS_NSUM + t - 50]);
    } else if (t < 150) {
        den_l[t] = pi[t - 100];
    } else if (t >= 160 && t < 168) {
        sw_l[t - 160] = ws[WS_SW + v0 + (t - 160)];
    }
    for (int e = t; e < 8*64; e += 256) {
        int b = e >> 3, vl = e & 7;
        bow_l[vl*64 + b] = (unsigned short)bow[b*Vc + v0 + vl];
    }
    if (t == 0) qz_l = 0.f;
    __syncthreads();

    // ---- coefficient build (400 elems, contiguous input reads) ----
    for (int i = t; i < 8*50; i += 256) {
        int vl = i / 50, k = i - vl*50;
        int g = v0*50 + i;
        float sv = seeds[g], en = exp_n[g], es = exp_s[g];
        float pk = den_l[100 + k];
        float st = (0.1f + es) * den_l[k];
        float rt = (0.1f + en) * den_l[50 + k];
        float sc = sv*st*pk;
        float n1 = sv*rt*(1.f - pk);
        float n2 = (1.f - sv)*rt;
        cd_l[i] = make_float2(sc + n1, n2);
        float ge = fmaf(pk, sc, (1.f - pk)*n1);
        float gf = (sw_l[vl] != 0.f) ? (1.f - pk)*n2 : n2;
        gg_l[i] = make_float2(ge, gf);
        n1_l[i] = n1;
    }
    __syncthreads();

    // ---- main loop: lane = b; wave w owns vl = 2w, 2w+1 (pair overlaps) ----
    {
        float pm[Kc];
#pragma unroll
        for (int k = 0; k < Kc; ++k) pm[k] = 0.f;
        float qzacc0 = 0.f, qzacc1 = 0.f;

#pragma unroll 2
        for (int jj = 0; jj < 2; ++jj) {
            const int vl = w*2 + jj;
            const float bw = (float)bow_l[vl*64 + lane];
            const float4* cd4 = (const float4*)(cd_l + vl*50);
            // phase A: S,R (theta from LDS; no reg array)
            float S = 0.f, S2 = 0.f, R = 0.f, R2 = 0.f;
#pragma unroll 5
            for (int k2 = 0; k2 < 25; ++k2) {
                float th0 = th_l[lane*51 + 2*k2];
                float th1 = th_l[lane*51 + 2*k2 + 1];
                float4 q = cd4[k2];
                S  = fmaf(th0, q.x, S);  R  = fmaf(th0, q.y, R);
                S2 = fmaf(th1, q.z, S2); R2 = fmaf(th1, q.w, R2);
            }
            S += S2; R += R2;
            const bool msk = bw > 0.f;
            const float is = msk ? 1.f/(S + 1e-6f) : 0.f;
            const float ir = msk ? 1.f/(R + 1e-6f) : 0.f;
            ii_l[vl*64 + lane] = make_float2(is, ir);
            // phase B: qz (log2 domain) + pm (full unroll: static pm idx)
            const float4* gg4 = (const float4*)(gg_l + vl*50);
#pragma unroll
            for (int k2 = 0; k2 < 25; ++k2) {
                float th0 = th_l[lane*51 + 2*k2];
                float th1 = th_l[lane*51 + 2*k2 + 1];
                float4 q = gg4[k2];
                float t1a = fmaf(q.x, is, q.y*ir);
                float t1b = fmaf(q.z, is, q.w*ir);
                float ga = th0*t1a;
                float gb = th1*t1b;
                qzacc0 = fmaf(ga, __log2f(ga + 1e-6f), qzacc0);
                qzacc1 = fmaf(gb, __log2f(gb + 1e-6f), qzacc1);
                pm[2*k2]   = fmaf(bw, t1a, pm[2*k2]);
                pm[2*k2+1] = fmaf(bw, t1b, pm[2*k2+1]);
            }
        }

        float qz = qzacc0 + qzacc1;
        for (int off = 32; off; off >>= 1) qz += __shfl_xor(qz, off);
        if (lane == 0) atomicAdd(&qz_l, qz);

        // pm merge: sequential per-wave passes (no LDS atomics)
        for (int ww = 0; ww < 4; ++ww) {
            if (w == ww) {
#pragma unroll
                for (int k = 0; k < Kc; ++k) pmb[lane*51 + k] += pm[k];
            }
            __syncthreads();
        }
    }
    // barrier above also covers ii_l / qz_l completion

    // ---- flush pm to 32 XCD-local shards (overlaps phase C issue) ----
    const int psh = (id & 7)*4 + ((id >> 3) & 3);
    for (int i = t; i < Bc*Kc; i += 256) {
        int b = i / 50, k = i - b*50;
        atomicAdd(&ws[WS_PM + psh*3200 + i], pmb[b*51 + k]);
    }
    if (t == 0) atomicAdd(&ws[WS_QZSH + (id & 31)], qz_l);

    // ---- phase C: lane = k; wave w owns vA=2w, vB=2w+1; final n/s writes ----
    {
        const float bC = (float)(((const int*)ws)[WS_BATCHC]);
        const float rs = rho * (1e7f / bC);
        const int vA = w*2, vB = w*2 + 1;
        float PTa=0.f, QTa=0.f, P2a=0.f, PTb=0.f, QTb=0.f, P2b=0.f;
#pragma unroll 8
        for (int b = 0; b < Bc; ++b) {
            float thv = th_l[b*51 + lane];
            float2 ua = ii_l[vA*64 + b];
            float2 ub = ii_l[vB*64 + b];
            float ba = (float)bow_l[vA*64 + b];
            float bb = (float)bow_l[vB*64 + b];
            PTa = fmaf(ba*ua.x, thv, PTa); QTa = fmaf(ba*ua.y, thv, QTa); P2a = fmaf(ua.x, thv, P2a);
            PTb = fmaf(bb*ub.x, thv, PTb); QTb = fmaf(bb*ub.y, thv, QTb); P2b = fmaf(ub.x, thv, P2b);
        }
        if (lane < Kc) {
            float gacc, ssn;
            {
                const int li = vA*50 + lane;
                const int g  = (v0 + vA)*50 + lane;
                float n1v = n1_l[li];
                float2 cdv = cd_l[li];
                float tn  = fmaf(n1v, PTa, cdv.y*QTa);
                float tsv = (cdv.x - n1v)*PTa;
                out[3200 + g]          = fmaf(omr, exp_n[g], rs*tn);
                float snew             = fmaf(omr, exp_s[g], rs*tsv);
                out[3200 + 400000 + g] = snew;
                gacc = n1v*P2a;
                ssn  = snew;
            }
            {
                const int li = vB*50 + lane;
                const int g  = (v0 + vB)*50 + lane;
                float n1v = n1_l[li];
                float2 cdv = cd_l[li];
                float tn  = fmaf(n1v, PTb, cdv.y*QTb);
                float tsv = (cdv.x - n1v)*PTb;
                out[3200 + g]          = fmaf(omr, exp_n[g], rs*tn);
                float snew             = fmaf(omr, exp_s[g], rs*tsv);
                out[3200 + 400000 + g] = snew;
                gacc = fmaf(n1v, P2b, gacc);
                ssn += snew;
            }
            atomicAdd(&ws[WS_GSRSH + (id & 63)*Kc + lane], gacc);
            atomicAdd(&ws[WS_SSNSH + (id & 31)*Kc + lane], ssn);
        }
    }
}

// ---------------- kEnd: m finalize + pi + qz ---------------------------------
__global__ __launch_bounds__(256) void kEnd(const int* __restrict__ itern_p,
    float* __restrict__ out, float* __restrict__ ws)
{
    const int t = threadIdx.x, blk = blockIdx.x;
    int ii = itern_p[0];
    float itern = (ii >= 0 && ii < 1000000) ? (float)ii : __int_as_float(ii);
    const float rho = 1.f / powf(itern + 5.f, 0.9f);
    const float omr = 1.f - rho;

    if (blk < 13) {
        int i = blk*256 + t;
        if (i < Bc*Kc) {
            float th = ws[WS_TH + i];
            float pmsum = 0.f;
#pragma unroll
            for (int s = 0; s < 32; ++s) pmsum += ws[WS_PM + s*3200 + i];
            out[i] = fmaf(omr, th - 0.1f, rho*th*pmsum);
        }
    } else {
        if (t < Kc) {
            float ssn = 0.f, srs = 0.f;
#pragma unroll
            for (int s = 0; s < 32; ++s) ssn += ws[WS_SSNSH + s*Kc + t];
#pragma unroll
            for (int s = 0; s < 64; ++s) srs += ws[WS_GSRSH + s*Kc + t];
            float p = ssn / (ssn + srs + 1e-6f);
            out[Bc*Kc + 2*Vc*Kc + t] = (p > 0.1f) ? p : 0.7f;
        }
        if (t == 63) {
            float qz = 0.f;
            for (int s = 0; s < 32; ++s) qz += ws[WS_QZSH + s];
            out[Bc*Kc + 2*Vc*Kc + Kc] = qz * 0.6931471805599453f;  // log2 -> ln
        }
    }
}

// ================= Fallback path (round-1 monolith, small ws) ================
__global__ __launch_bounds__(256) void fb_k1(const int* __restrict__ bow,
    const float* __restrict__ seeds, const float* __restrict__ exp_n,
    const float* __restrict__ exp_s, float* __restrict__ ws)
{
    __shared__ float redf[256];
    __shared__ int   redi[256];
    const int t = threadIdx.x, blk = blockIdx.x;
    if (blk < Kc) {
        float sn = 0.f, ss = 0.f;
        for (int v = t; v < Vc; v += 256) {
            sn += exp_n[v*Kc + blk];
            ss += exp_s[v*Kc + blk];
        }
        redf[t] = sn; __syncthreads();
        for (int s = 128; s > 0; s >>= 1) { if (t < s) redf[t] += redf[t+s]; __syncthreads(); }
        if (t == 0) ws[WS_NSUM + blk] = redf[0];
        __syncthreads();
        redf[t] = ss; __syncthreads();
        for (int s = 128; s > 0; s >>= 1) { if (t < s) redf[t] += redf[t+s]; __syncthreads(); }
        if (t == 0) ws[WS_SSUM + blk] = redf[0];
    } else if (blk < Kc + 32) {
        int acc = 0;
        for (int i = (blk - Kc)*256 + t; i < Bc*Vc; i += 32*256) acc += bow[i];
        redi[t] = acc; __syncthreads();
        for (int s = 128; s > 0; s >>= 1) { if (t < s) redi[t] += redi[t+s]; __syncthreads(); }
        if (t == 0) atomicAdd((int*)ws + WS_BATCHC, redi[0]);
    } else {
        int cnt = 0;
        for (int v = (blk - Kc - 32)*256 + t; v < Vc; v += 8*256) {
            const float* row = seeds + v*Kc;
            int any = 0;
            for (int k = 0; k < Kc; ++k) any |= (row[k] != 0.f);
            cnt += any;
        }
        redi[t] = cnt; __syncthreads();
        for (int s = 128; s > 0; s >>= 1) { if (t < s) redi[t] += redi[t+s]; __syncthreads(); }
        if (t == 0) atomicAdd((int*)ws + WS_SCNT, redi[0]);
    }
}

__global__ __launch_bounds__(512) void fb_k2(
    const int* __restrict__ bow, const int* __restrict__ bidx,
    const float* __restrict__ seeds, const float* __restrict__ exp_m,
    const float* __restrict__ exp_n, const float* __restrict__ exp_s,
    const float* __restrict__ pi, float* __restrict__ ws,
    float* __restrict__ out)
{
    float* out_m = out;
    float* out_n = out + Bc*Kc;
    float* out_s = out + Bc*Kc + Vc*Kc;
    __shared__ float lds_m[Bc*Kc];
    __shared__ float lds_theta[Bc*Kc];
    __shared__ float lds_srsum[Kc];
    __shared__ float lds_qz;
    const int t = threadIdx.x;
    for (int i = t; i < Bc*Kc; i += 512) lds_m[i] = 0.f;
    if (t < Kc) lds_srsum[t] = 0.f;
    if (t == 0) lds_qz = 0.f;
    for (int i = t; i < Bc*Kc; i += 512) {
        int b = i / Kc;
        lds_theta[i] = exp_m[bidx[b]*Kc + (i - b*Kc)] + 0.1f;
    }
    __syncthreads();
    const int lane = t & 63, wid = t >> 6;
    const int gw = blockIdx.x*8 + wid, nw = gridDim.x*8;
    const int k = lane;
    const bool kval = (k < Kc);
    const float S_f = (float)(((const int*)ws)[WS_SCNT]);
    float pi_k = 0.f, omp_k = 0.f, sden_inv = 0.f, rden_inv = 0.f;
    if (kval) {
        pi_k = pi[k]; omp_k = 1.f - pi_k;
        sden_inv = 1.f / (0.1f*S_f + ws[WS_SSUM + k]);
        rden_inv = 1.f / (0.1f*(float)Vc + ws[WS_NSUM + k]);
    }
    float acc_sr = 0.f, acc_qz = 0.f;
    for (int v = gw; v < Vc; v += nw) {
        float seeds_vk = 0.f, es = 0.f, en = 0.f;
        if (kval) { seeds_vk = seeds[v*Kc+k]; es = exp_s[v*Kc+k]; en = exp_n[v*Kc+k]; }
        const float st = (0.1f + es)*sden_inv;
        const float rt = (0.1f + en)*rden_inv;
        const bool seed_word = (__ballot(seeds_vk != 0.f) != 0ULL);
        const float bow_lane = (float)bow[lane*Vc + v];
        float acc_n = 0.f, acc_s = 0.f;
        for (int b = 0; b < Bc; ++b) {
            const float bw = __shfl(bow_lane, b);
            if (bw == 0.f) continue;
            const float th = lds_theta[b*Kc + (kval ? k : 0)];
            float ss = seeds_vk*th*st*pi_k;
            float sr = seeds_vk*th*rt*omp_k;
            float rr = (1.f - seeds_vk)*th*rt;
            float ssum = ss + sr, rsum = rr;
            for (int off = 32; off > 0; off >>= 1) {
                ssum += __shfl_xor(ssum, off);
                rsum += __shfl_xor(rsum, off);
            }
            const float inv_s = __builtin_amdgcn_rcpf(ssum + 1e-6f);
            const float inv_r = __builtin_amdgcn_rcpf(rsum + 1e-6f);
            const float ssn = ss*inv_s, srn = sr*inv_s, rrn = rr*inv_r;
            const float g = seed_word ? (pi_k*ssn + omp_k*(srn + rrn)) : rrn;
            acc_n += (srn + rrn)*bw;
            acc_s += ssn*bw;
            acc_sr += srn;
            acc_qz += g*__logf(g + 1e-6f);
            if (kval) atomicAdd(&lds_m[b*Kc + k], g*bw);
        }
        if (kval) { out_n[v*Kc + k] = acc_n; out_s[v*Kc + k] = acc_s; }
    }
    if (kval) atomicAdd(&lds_srsum[k], acc_sr);
    for (int off = 32; off > 0; off >>= 1) acc_qz += __shfl_xor(acc_qz, off);
    if (lane == 0) atomicAdd(&lds_qz, acc_qz);
    __syncthreads();
    for (int i = t; i < Bc*Kc; i += 512) {
        float vtm = lds_m[i];
        if (vtm != 0.f) atomicAdd(&out_m[i], vtm);
    }
    if (t < Kc) atomicAdd(&ws[FB_GSR + t], lds_srsum[t]);
    if (t == 0) atomicAdd(&ws[FB_QZ], lds_qz);
}

__global__ __launch_bounds__(256) void fb_k3(
    const float* __restrict__ exp_m, const float* __restrict__ exp_n,
    const float* __restrict__ exp_s, const int* __restrict__ bidx,
    const int* __restrict__ itern_p, float* __restrict__ out,
    float* __restrict__ ws)
{
    const int t = threadIdx.x, blk = blockIdx.x;
    int ii = itern_p[0];
    float itern = (ii >= 0 && ii < 1000000) ? (float)ii : __int_as_float(ii);
    const float rho = 1.f / powf(itern + 5.f, 0.9f);
    const float omr = 1.f - rho;
    const float bC = (float)(((const int*)ws)[WS_BATCHC]);
    const float scale = 1e7f / bC;
    float* out_m = out;
    float* out_n = out + Bc*Kc;
    float* out_s = out + Bc*Kc + Vc*Kc;
    if (blk < Kc) {
        const int k = blk;
        float acc = 0.f;
        for (int v = t; v < Vc; v += 256) {
            int i = v*Kc + k;
            out_n[i] = omr*exp_n[i] + rho*scale*out_n[i];
            float snew = omr*exp_s[i] + rho*scale*out_s[i];
            out_s[i] = snew;
            acc += snew;
        }
        __shared__ float redf[256];
        redf[t] = acc; __syncthreads();
        for (int s = 128; s > 0; s >>= 1) { if (t < s) redf[t] += redf[t+s]; __syncthreads(); }
        if (t == 0) atomicAdd(&ws[FB_SSN + k], redf[0]);
    } else {
        for (int i = t; i < Bc*Kc; i += 256) {
            int b = i / Kc;
            out_m[i] = omr*exp_m[bidx[b]*Kc + (i - b*Kc)] + rho*out_m[i];
        }
        if (t == 0) out[Bc*Kc + 2*Vc*Kc + Kc] = ws[FB_QZ];
    }
}

__global__ void fb_k4(const float* __restrict__ ws, float* __restrict__ out) {
    int k = threadIdx.x;
    if (k < Kc) {
        float ssn = ws[FB_SSN + k];
        float srs = ws[FB_GSR + k];
        float p = ssn / (ssn + srs + 1e-6f);
        out[Bc*Kc + 2*Vc*Kc + k] = (p > 0.1f) ? p : 0.7f;
    }
}

// =============================================================================
extern "C" void kernel_launch(void* const* d_in, const int* in_sizes, int n_in,
                              void* d_out, int out_size, void* d_ws, size_t ws_size,
                              hipStream_t stream)
{
    const int*   bow    = (const int*)d_in[0];
    const int*   bidx   = (const int*)d_in[1];
    const float* seeds  = (const float*)d_in[2];
    const float* exp_m  = (const float*)d_in[3];
    const float* exp_n  = (const float*)d_in[4];
    const float* exp_s  = (const float*)d_in[5];
    const float* pi     = (const float*)d_in[6];
    const int*   iter_n = (const int*)d_in[7];
    float* out = (float*)d_out;
    float* ws  = (float*)d_ws;

    if (ws_size >= (size_t)WS_END * sizeof(float)) {
        hipMemsetAsync(d_ws, 0, 1024, stream);   // only k1's atomic targets
        k1_pre<<<244, 256, 0, stream>>>(bow, seeds, exp_n, exp_s, bidx, exp_m, ws);
        kF<<<1008, 256, 0, stream>>>(bow, seeds, exp_n, exp_s, pi, iter_n, ws, out);
        kEnd<<<14, 256, 0, stream>>>(iter_n, out, ws);
    } else {
        size_t zb = 2048;
        if (zb > ws_size) zb = ws_size;
        hipMemsetAsync(d_ws, 0, zb, stream);
        hipMemsetAsync(d_out, 0, Bc*Kc*sizeof(float), stream);
        fb_k1<<<Kc + 32 + 8, 256, 0, stream>>>(bow, seeds, exp_n, exp_s, ws);
        fb_k2<<<256, 512, 0, stream>>>(bow, bidx, seeds, exp_m, exp_n, exp_s, pi, ws, out);
        fb_k3<<<Kc + 1, 256, 0, stream>>>(exp_m, exp_n, exp_s, bidx, iter_n, out, ws);
        fb_k4<<<1, 64, 0, stream>>>(ws, out);
    }
}

// Round 19
// 46.101 us; speedup vs baseline: 1.1759x; 1.1759x over previous
//
#include <hip/hip_runtime.h>
#include <math.h>

constexpr int Bc = 64;      // batch
constexpr int Vc = 8000;    // vocab
constexpr int Kc = 50;      // topics

// ws float-offsets
#define WS_NSUM   0        // 50  exp_n colsum (atomic)
#define WS_SSUM   50       // 50  exp_s colsum (atomic)
#define WS_BATCHC 151      // batch_C (atomic int)
#define WS_SCNT   152      // seed-word count (atomic int)
#define WS_QZSH   160      // 32 qz shards -> 192
#define WS_PM     256      // 16 shards x 3200 -> 51456  (zeroed by k1 spare blocks)
#define WS_GSRSH  51456    // 64*50 gamma_sr_sum shards -> 54656
#define WS_SSNSH  54656    // 32*50 exp_s_sum_new shards -> 56256
#define WS_ZEND   56256    // end of accumulator region
#define WS_TH     56256    // 3200 theta[b][k] -> 59456
#define WS_SW     59456    // 8000 seed-word flags -> 67456
#define WS_END    67456    // 270 KB

// fallback-only small offsets
#define FB_QZ     150
#define FB_GSR    200      // 50
#define FB_SSN    256      // 50

// ---------------- k1: colsums, batchC, flags, theta + PM-region zeroing ------
__global__ __launch_bounds__(256) void k1_pre(const int* __restrict__ bow,
    const float* __restrict__ seeds, const float* __restrict__ exp_n,
    const float* __restrict__ exp_s, const int* __restrict__ bidx,
    const float* __restrict__ exp_m, float* __restrict__ ws)
{
    const int t = threadIdx.x, blk = blockIdx.x;
    if (blk < 100) {
        __shared__ float csn[Kc], css[Kc];
        if (t < Kc) { csn[t] = 0.f; css[t] = 0.f; }
        __syncthreads();
        const int l = t & 63, w = t >> 6;
        const int q = (blk >> 1)*64 + l;     // 0..3199
        const int k = q % 50;
        float sn = 0.f, ss = 0.f;
        for (int j = w + (blk & 1)*4; j < 125; j += 8) {
            int flat = j*3200 + q;           // coalesced
            sn += exp_n[flat];
            ss += exp_s[flat];
        }
        atomicAdd(&csn[k], sn);
        atomicAdd(&css[k], ss);
        __syncthreads();
        if (t < Kc) {
            atomicAdd(&ws[WS_NSUM + t], csn[t]);
            atomicAdd(&ws[WS_SSUM + t], css[t]);
        }
    } else if (blk < 164) {
        const int4* b4 = (const int4*)bow;
        int acc = 0;
        for (int i = (blk-100)*256 + t; i < Bc*Vc/4; i += 64*256) {
            int4 x = b4[i];
            acc += x.x + x.y + x.z + x.w;
        }
        for (int off = 32; off; off >>= 1) acc += __shfl_xor(acc, off);
        __shared__ int ri[4];
        if ((t & 63) == 0) ri[t >> 6] = acc;
        __syncthreads();
        if (t == 0) atomicAdd((int*)ws + WS_BATCHC, ri[0]+ri[1]+ri[2]+ri[3]);
    } else if (blk < 196) {
        int v = (blk-164)*256 + t;
        int any = 0;
        if (v < Vc) {
            const float2* rp = (const float2*)(seeds + v*Kc);
            for (int j = 0; j < 25; ++j) {
                float2 x = rp[j];
                any |= (x.x != 0.f) | (x.y != 0.f);
            }
            ws[WS_SW + v] = any ? 1.f : 0.f;
        }
        unsigned long long m = __ballot(any);
        if ((t & 63) == 0) atomicAdd((int*)ws + WS_SCNT, (int)__popcll(m));
    } else if (blk < 197) {
        for (int i = t; i < Bc*Kc; i += 256) {
            int b = i / Kc, k = i - b*Kc;
            ws[WS_TH + i] = exp_m[bidx[b]*Kc + k] + 0.1f;
        }
    } else {
        // zero the big accumulator region [256, WS_ZEND) (25 blocks).
        // Race-free: k1's own atomics only touch [0,256); kF (stream-ordered
        // after k1) is the only writer of this region.
        int base = 256 + (blk - 197)*2304 + t;
#pragma unroll
        for (int j = 0; j < 9; ++j) {
            int idx = base + j*256;
            if (idx < WS_ZEND) ws[idx] = 0.f;
        }
    }
}

// ---------------- kF: fused middle + final n/s write -------------------------
// Terminal form (measured best 46.1-46.5us total, VGPR 84, no spill):
// 256 thr, 4 waves x 4 v, 53KB LDS, 504 blocks XCD-pinned; theta from LDS
// (reg-theta spills: r11/r16); pm[50] in regs w/ static indices; sequential
// pm merge; log2-domain qz; jj unroll 2; A-loop unroll 5; exact divides.
// Tile A/B: 8-v tile regressed (r18, overhead doubling); 512-thr regressed
// (r13); min-waves hints force spill (r10).
__global__ __launch_bounds__(256) void kF(const int* __restrict__ bow,
    const float* __restrict__ seeds, const float* __restrict__ exp_n,
    const float* __restrict__ exp_s, const float* __restrict__ pi,
    const int* __restrict__ itern_p, float* __restrict__ ws,
    float* __restrict__ out)
{
    const int id = blockIdx.x;
    const int vt = (id & 7)*63 + (id >> 3);   // XCD-pinned v-tile (16 v)
    if (vt >= Vc/16) return;                  // block-uniform (504 > 500 tiles)
    const int v0 = vt * 16;

    __shared__ float  th_l[64*51];       // 13056 B  theta [b][k] stride 51
    __shared__ float  pmb[64*51];        // 13056 B  pm accum [b][k] stride 51
    __shared__ float2 cd_l[16*50];       //  6400 B  (C,D)
    __shared__ float2 gg_l[16*50];       //  6400 B  (GE,GF)
    __shared__ float  n1_l[16*50];       //  3200 B
    __shared__ float2 ii_l[16*64];       //  8192 B  (is, ir)
    __shared__ unsigned short bow_l[16*64]; // 2048 B
    __shared__ float  den_l[152];        // invS|invR|pi
    __shared__ float  sw_l[16];
    __shared__ float  qz_l;

    const int t = threadIdx.x, lane = t & 63, w = t >> 6;

    int ii = itern_p[0];
    float itern = (ii >= 0 && ii < 1000000) ? (float)ii : __int_as_float(ii);
    const float rho = 1.f / powf(itern + 5.f, 0.9f);
    const float omr = 1.f - rho;

    // ---- staging ----
    for (int i = t; i < Bc*Kc; i += 256) {
        int b = i / 50, k = i - b*50;
        th_l[b*51 + k] = ws[WS_TH + i];
        pmb[b*51 + k]  = 0.f;
    }
    if (t < 50) {
        float Sf = (float)(((const int*)ws)[WS_SCNT]);
        den_l[t] = 1.f / (0.1f*Sf + ws[WS_SSUM + t]);
    } else if (t < 100) {
        den_l[t] = 1.f / (0.1f*(float)Vc + ws[WS_NSUM + t - 50]);
    } else if (t < 150) {
        den_l[t] = pi[t - 100];
    } else if (t >= 160 && t < 176) {
        sw_l[t - 160] = ws[WS_SW + v0 + (t - 160)];
    }
    for (int e = t; e < 16*64; e += 256) {
        int b = e >> 4, vl = e & 15;
        bow_l[vl*64 + b] = (unsigned short)bow[b*Vc + v0 + vl];
    }
    if (t == 0) qz_l = 0.f;
    __syncthreads();

    // ---- coefficient build (800 elems, contiguous input reads) ----
    for (int i = t; i < 16*50; i += 256) {
        int vl = i / 50, k = i - vl*50;
        int g = v0*50 + i;
        float sv = seeds[g], en = exp_n[g], es = exp_s[g];
        float pk = den_l[100 + k];
        float st = (0.1f + es) * den_l[k];
        float rt = (0.1f + en) * den_l[50 + k];
        float sc = sv*st*pk;
        float n1 = sv*rt*(1.f - pk);
        float n2 = (1.f - sv)*rt;
        cd_l[i] = make_float2(sc + n1, n2);
        float ge = fmaf(pk, sc, (1.f - pk)*n1);
        float gf = (sw_l[vl] != 0.f) ? (1.f - pk)*n2 : n2;
        gg_l[i] = make_float2(ge, gf);
        n1_l[i] = n1;
    }
    __syncthreads();

    // ---- main loop: lane = b; wave w owns vl = 4w .. 4w+3 (pairs overlap) ---
    {
        float pm[Kc];
#pragma unroll
        for (int k = 0; k < Kc; ++k) pm[k] = 0.f;
        float qzacc0 = 0.f, qzacc1 = 0.f;

#pragma unroll 2
        for (int jj = 0; jj < 4; ++jj) {
            const int vl = w*4 + jj;
            const float bw = (float)bow_l[vl*64 + lane];
            const float4* cd4 = (const float4*)(cd_l + vl*50);
            // phase A: S,R (theta from LDS; no reg array)
            float S = 0.f, S2 = 0.f, R = 0.f, R2 = 0.f;
#pragma unroll 5
            for (int k2 = 0; k2 < 25; ++k2) {
                float th0 = th_l[lane*51 + 2*k2];
                float th1 = th_l[lane*51 + 2*k2 + 1];
                float4 q = cd4[k2];
                S  = fmaf(th0, q.x, S);  R  = fmaf(th0, q.y, R);
                S2 = fmaf(th1, q.z, S2); R2 = fmaf(th1, q.w, R2);
            }
            S += S2; R += R2;
            const bool msk = bw > 0.f;
            const float is = msk ? 1.f/(S + 1e-6f) : 0.f;
            const float ir = msk ? 1.f/(R + 1e-6f) : 0.f;
            ii_l[vl*64 + lane] = make_float2(is, ir);
            // phase B: qz (log2 domain) + pm (full unroll: static pm idx)
            const float4* gg4 = (const float4*)(gg_l + vl*50);
#pragma unroll
            for (int k2 = 0; k2 < 25; ++k2) {
                float th0 = th_l[lane*51 + 2*k2];
                float th1 = th_l[lane*51 + 2*k2 + 1];
                float4 q = gg4[k2];
                float t1a = fmaf(q.x, is, q.y*ir);
                float t1b = fmaf(q.z, is, q.w*ir);
                float ga = th0*t1a;
                float gb = th1*t1b;
                qzacc0 = fmaf(ga, __log2f(ga + 1e-6f), qzacc0);
                qzacc1 = fmaf(gb, __log2f(gb + 1e-6f), qzacc1);
                pm[2*k2]   = fmaf(bw, t1a, pm[2*k2]);
                pm[2*k2+1] = fmaf(bw, t1b, pm[2*k2+1]);
            }
        }

        float qz = qzacc0 + qzacc1;
        for (int off = 32; off; off >>= 1) qz += __shfl_xor(qz, off);
        if (lane == 0) atomicAdd(&qz_l, qz);

        // pm merge: sequential per-wave passes (no LDS atomics)
        for (int ww = 0; ww < 4; ++ww) {
            if (w == ww) {
#pragma unroll
                for (int k = 0; k < Kc; ++k) pmb[lane*51 + k] += pm[k];
            }
            __syncthreads();
        }
    }
    // barrier above also covers ii_l / qz_l completion

    // ---- flush pm to 16 XCD-local shards (overlaps phase C issue) ----
    const int psh = (id & 7)*2 + ((id >> 3) & 1);
    for (int i = t; i < Bc*Kc; i += 256) {
        int b = i / 50, k = i - b*50;
        atomicAdd(&ws[WS_PM + psh*3200 + i], pmb[b*51 + k]);
    }
    if (t == 0) atomicAdd(&ws[WS_QZSH + (id & 31)], qz_l);

    // ---- phase C: lane = k; wave w owns vl = 4w..4w+3; final n/s writes ----
    {
        const float bC = (float)(((const int*)ws)[WS_BATCHC]);
        const float rs = rho * (1e7f / bC);
        float PT0=0.f,PT1=0.f,PT2=0.f,PT3=0.f;
        float QT0=0.f,QT1=0.f,QT2=0.f,QT3=0.f;
        float P20=0.f,P21=0.f,P22=0.f,P23=0.f;
#pragma unroll 8
        for (int b = 0; b < Bc; ++b) {
            float thv = th_l[b*51 + lane];
            float2 u0 = ii_l[(w*4+0)*64 + b];
            float2 u1 = ii_l[(w*4+1)*64 + b];
            float2 u2 = ii_l[(w*4+2)*64 + b];
            float2 u3 = ii_l[(w*4+3)*64 + b];
            float b0 = (float)bow_l[(w*4+0)*64 + b];
            float b1 = (float)bow_l[(w*4+1)*64 + b];
            float b2 = (float)bow_l[(w*4+2)*64 + b];
            float b3 = (float)bow_l[(w*4+3)*64 + b];
            PT0 = fmaf(b0*u0.x, thv, PT0); QT0 = fmaf(b0*u0.y, thv, QT0); P20 = fmaf(u0.x, thv, P20);
            PT1 = fmaf(b1*u1.x, thv, PT1); QT1 = fmaf(b1*u1.y, thv, QT1); P21 = fmaf(u1.x, thv, P21);
            PT2 = fmaf(b2*u2.x, thv, PT2); QT2 = fmaf(b2*u2.y, thv, QT2); P22 = fmaf(u2.x, thv, P22);
            PT3 = fmaf(b3*u3.x, thv, PT3); QT3 = fmaf(b3*u3.y, thv, QT3); P23 = fmaf(u3.x, thv, P23);
        }
        if (lane < Kc) {
            float PT[4] = {PT0, PT1, PT2, PT3};
            float QT[4] = {QT0, QT1, QT2, QT3};
            float P2[4] = {P20, P21, P22, P23};
            float gacc = 0.f, ssn = 0.f;
#pragma unroll
            for (int jj = 0; jj < 4; ++jj) {
                const int vl = w*4 + jj;
                const int li = vl*50 + lane;
                const int g  = (v0 + vl)*50 + lane;
                float n1v = n1_l[li];
                float2 cdv = cd_l[li];
                float tn  = fmaf(n1v, PT[jj], cdv.y*QT[jj]);
                float tsv = (cdv.x - n1v)*PT[jj];
                out[3200 + g]          = fmaf(omr, exp_n[g], rs*tn);
                float snew             = fmaf(omr, exp_s[g], rs*tsv);
                out[3200 + 400000 + g] = snew;
                gacc = fmaf(n1v, P2[jj], gacc);
                ssn += snew;
            }
            atomicAdd(&ws[WS_GSRSH + (id & 63)*Kc + lane], gacc);
            atomicAdd(&ws[WS_SSNSH + (id & 31)*Kc + lane], ssn);
        }
    }
}

// ---------------- kEnd: m finalize + pi + qz ---------------------------------
__global__ __launch_bounds__(256) void kEnd(const int* __restrict__ itern_p,
    float* __restrict__ out, float* __restrict__ ws)
{
    const int t = threadIdx.x, blk = blockIdx.x;
    int ii = itern_p[0];
    float itern = (ii >= 0 && ii < 1000000) ? (float)ii : __int_as_float(ii);
    const float rho = 1.f / powf(itern + 5.f, 0.9f);
    const float omr = 1.f - rho;

    if (blk < 13) {
        int i = blk*256 + t;
        if (i < Bc*Kc) {
            float th = ws[WS_TH + i];
            float pmsum = 0.f;
#pragma unroll
            for (int s = 0; s < 16; ++s) pmsum += ws[WS_PM + s*3200 + i];
            out[i] = fmaf(omr, th - 0.1f, rho*th*pmsum);
        }
    } else {
        if (t < Kc) {
            float ssn = 0.f, srs = 0.f;
#pragma unroll
            for (int s = 0; s < 32; ++s) ssn += ws[WS_SSNSH + s*Kc + t];
#pragma unroll
            for (int s = 0; s < 64; ++s) srs += ws[WS_GSRSH + s*Kc + t];
            float p = ssn / (ssn + srs + 1e-6f);
            out[Bc*Kc + 2*Vc*Kc + t] = (p > 0.1f) ? p : 0.7f;
        }
        if (t == 63) {
            float qz = 0.f;
            for (int s = 0; s < 32; ++s) qz += ws[WS_QZSH + s];
            out[Bc*Kc + 2*Vc*Kc + Kc] = qz * 0.6931471805599453f;  // log2 -> ln
        }
    }
}

// ================= Fallback path (round-1 monolith, small ws) ================
__global__ __launch_bounds__(256) void fb_k1(const int* __restrict__ bow,
    const float* __restrict__ seeds, const float* __restrict__ exp_n,
    const float* __restrict__ exp_s, float* __restrict__ ws)
{
    __shared__ float redf[256];
    __shared__ int   redi[256];
    const int t = threadIdx.x, blk = blockIdx.x;
    if (blk < Kc) {
        float sn = 0.f, ss = 0.f;
        for (int v = t; v < Vc; v += 256) {
            sn += exp_n[v*Kc + blk];
            ss += exp_s[v*Kc + blk];
        }
        redf[t] = sn; __syncthreads();
        for (int s = 128; s > 0; s >>= 1) { if (t < s) redf[t] += redf[t+s]; __syncthreads(); }
        if (t == 0) ws[WS_NSUM + blk] = redf[0];
        __syncthreads();
        redf[t] = ss; __syncthreads();
        for (int s = 128; s > 0; s >>= 1) { if (t < s) redf[t] += redf[t+s]; __syncthreads(); }
        if (t == 0) ws[WS_SSUM + blk] = redf[0];
    } else if (blk < Kc + 32) {
        int acc = 0;
        for (int i = (blk - Kc)*256 + t; i < Bc*Vc; i += 32*256) acc += bow[i];
        redi[t] = acc; __syncthreads();
        for (int s = 128; s > 0; s >>= 1) { if (t < s) redi[t] += redi[t+s]; __syncthreads(); }
        if (t == 0) atomicAdd((int*)ws + WS_BATCHC, redi[0]);
    } else {
        int cnt = 0;
        for (int v = (blk - Kc - 32)*256 + t; v < Vc; v += 8*256) {
            const float* row = seeds + v*Kc;
            int any = 0;
            for (int k = 0; k < Kc; ++k) any |= (row[k] != 0.f);
            cnt += any;
        }
        redi[t] = cnt; __syncthreads();
        for (int s = 128; s > 0; s >>= 1) { if (t < s) redi[t] += redi[t+s]; __syncthreads(); }
        if (t == 0) atomicAdd((int*)ws + WS_SCNT, redi[0]);
    }
}

__global__ __launch_bounds__(512) void fb_k2(
    const int* __restrict__ bow, const int* __restrict__ bidx,
    const float* __restrict__ seeds, const float* __restrict__ exp_m,
    const float* __restrict__ exp_n, const float* __restrict__ exp_s,
    const float* __restrict__ pi, float* __restrict__ ws,
    float* __restrict__ out)
{
    float* out_m = out;
    float* out_n = out + Bc*Kc;
    float* out_s = out + Bc*Kc + Vc*Kc;
    __shared__ float lds_m[Bc*Kc];
    __shared__ float lds_theta[Bc*Kc];
    __shared__ float lds_srsum[Kc];
    __shared__ float lds_qz;
    const int t = threadIdx.x;
    for (int i = t; i < Bc*Kc; i += 512) lds_m[i] = 0.f;
    if (t < Kc) lds_srsum[t] = 0.f;
    if (t == 0) lds_qz = 0.f;
    for (int i = t; i < Bc*Kc; i += 512) {
        int b = i / Kc;
        lds_theta[i] = exp_m[bidx[b]*Kc + (i - b*Kc)] + 0.1f;
    }
    __syncthreads();
    const int lane = t & 63, wid = t >> 6;
    const int gw = blockIdx.x*8 + wid, nw = gridDim.x*8;
    const int k = lane;
    const bool kval = (k < Kc);
    const float S_f = (float)(((const int*)ws)[WS_SCNT]);
    float pi_k = 0.f, omp_k = 0.f, sden_inv = 0.f, rden_inv = 0.f;
    if (kval) {
        pi_k = pi[k]; omp_k = 1.f - pi_k;
        sden_inv = 1.f / (0.1f*S_f + ws[WS_SSUM + k]);
        rden_inv = 1.f / (0.1f*(float)Vc + ws[WS_NSUM + k]);
    }
    float acc_sr = 0.f, acc_qz = 0.f;
    for (int v = gw; v < Vc; v += nw) {
        float seeds_vk = 0.f, es = 0.f, en = 0.f;
        if (kval) { seeds_vk = seeds[v*Kc+k]; es = exp_s[v*Kc+k]; en = exp_n[v*Kc+k]; }
        const float st = (0.1f + es)*sden_inv;
        const float rt = (0.1f + en)*rden_inv;
        const bool seed_word = (__ballot(seeds_vk != 0.f) != 0ULL);
        const float bow_lane = (float)bow[lane*Vc + v];
        float acc_n = 0.f, acc_s = 0.f;
        for (int b = 0; b < Bc; ++b) {
            const float bw = __shfl(bow_lane, b);
            if (bw == 0.f) continue;
            const float th = lds_theta[b*Kc + (kval ? k : 0)];
            float ss = seeds_vk*th*st*pi_k;
            float sr = seeds_vk*th*rt*omp_k;
            float rr = (1.f - seeds_vk)*th*rt;
            float ssum = ss + sr, rsum = rr;
            for (int off = 32; off > 0; off >>= 1) {
                ssum += __shfl_xor(ssum, off);
                rsum += __shfl_xor(rsum, off);
            }
            const float inv_s = __builtin_amdgcn_rcpf(ssum + 1e-6f);
            const float inv_r = __builtin_amdgcn_rcpf(rsum + 1e-6f);
            const float ssn = ss*inv_s, srn = sr*inv_s, rrn = rr*inv_r;
            const float g = seed_word ? (pi_k*ssn + omp_k*(srn + rrn)) : rrn;
            acc_n += (srn + rrn)*bw;
            acc_s += ssn*bw;
            acc_sr += srn;
            acc_qz += g*__logf(g + 1e-6f);
            if (kval) atomicAdd(&lds_m[b*Kc + k], g*bw);
        }
        if (kval) { out_n[v*Kc + k] = acc_n; out_s[v*Kc + k] = acc_s; }
    }
    if (kval) atomicAdd(&lds_srsum[k], acc_sr);
    for (int off = 32; off > 0; off >>= 1) acc_qz += __shfl_xor(acc_qz, off);
    if (lane == 0) atomicAdd(&lds_qz, acc_qz);
    __syncthreads();
    for (int i = t; i < Bc*Kc; i += 512) {
        float vtm = lds_m[i];
        if (vtm != 0.f) atomicAdd(&out_m[i], vtm);
    }
    if (t < Kc) atomicAdd(&ws[FB_GSR + t], lds_srsum[t]);
    if (t == 0) atomicAdd(&ws[FB_QZ], lds_qz);
}

__global__ __launch_bounds__(256) void fb_k3(
    const float* __restrict__ exp_m, const float* __restrict__ exp_n,
    const float* __restrict__ exp_s, const int* __restrict__ bidx,
    const int* __restrict__ itern_p, float* __restrict__ out,
    float* __restrict__ ws)
{
    const int t = threadIdx.x, blk = blockIdx.x;
    int ii = itern_p[0];
    float itern = (ii >= 0 && ii < 1000000) ? (float)ii : __int_as_float(ii);
    const float rho = 1.f / powf(itern + 5.f, 0.9f);
    const float omr = 1.f - rho;
    const float bC = (float)(((const int*)ws)[WS_BATCHC]);
    const float scale = 1e7f / bC;
    float* out_m = out;
    float* out_n = out + Bc*Kc;
    float* out_s = out + Bc*Kc + Vc*Kc;
    if (blk < Kc) {
        const int k = blk;
        float acc = 0.f;
        for (int v = t; v < Vc; v += 256) {
            int i = v*Kc + k;
            out_n[i] = omr*exp_n[i] + rho*scale*out_n[i];
            float snew = omr*exp_s[i] + rho*scale*out_s[i];
            out_s[i] = snew;
            acc += snew;
        }
        __shared__ float redf[256];
        redf[t] = acc; __syncthreads();
        for (int s = 128; s > 0; s >>= 1) { if (t < s) redf[t] += redf[t+s]; __syncthreads(); }
        if (t == 0) atomicAdd(&ws[FB_SSN + k], redf[0]);
    } else {
        for (int i = t; i < Bc*Kc; i += 256) {
            int b = i / Kc;
            out_m[i] = omr*exp_m[bidx[b]*Kc + (i - b*Kc)] + rho*out_m[i];
        }
        if (t == 0) out[Bc*Kc + 2*Vc*Kc + Kc] = ws[FB_QZ];
    }
}

__global__ void fb_k4(const float* __restrict__ ws, float* __restrict__ out) {
    int k = threadIdx.x;
    if (k < Kc) {
        float ssn = ws[FB_SSN + k];
        float srs = ws[FB_GSR + k];
        float p = ssn / (ssn + srs + 1e-6f);
        out[Bc*Kc + 2*Vc*Kc + k] = (p > 0.1f) ? p : 0.7f;
    }
}

// =============================================================================
extern "C" void kernel_launch(void* const* d_in, const int* in_sizes, int n_in,
                              void* d_out, int out_size, void* d_ws, size_t ws_size,
                              hipStream_t stream)
{
    const int*   bow    = (const int*)d_in[0];
    const int*   bidx   = (const int*)d_in[1];
    const float* seeds  = (const float*)d_in[2];
    const float* exp_m  = (const float*)d_in[3];
    const float* exp_n  = (const float*)d_in[4];
    const float* exp_s  = (const float*)d_in[5];
    const float* pi     = (const float*)d_in[6];
    const int*   iter_n = (const int*)d_in[7];
    float* out = (float*)d_out;
    float* ws  = (float*)d_ws;

    if (ws_size >= (size_t)WS_END * sizeof(float)) {
        hipMemsetAsync(d_ws, 0, 1024, stream);   // only k1's atomic targets
        k1_pre<<<222, 256, 0, stream>>>(bow, seeds, exp_n, exp_s, bidx, exp_m, ws);
        kF<<<504, 256, 0, stream>>>(bow, seeds, exp_n, exp_s, pi, iter_n, ws, out);
        kEnd<<<14, 256, 0, stream>>>(iter_n, out, ws);
    } else {
        size_t zb = 2048;
        if (zb > ws_size) zb = ws_size;
        hipMemsetAsync(d_ws, 0, zb, stream);
        hipMemsetAsync(d_out, 0, Bc*Kc*sizeof(float), stream);
        fb_k1<<<Kc + 32 + 8, 256, 0, stream>>>(bow, seeds, exp_n, exp_s, ws);
        fb_k2<<<256, 512, 0, stream>>>(bow, bidx, seeds, exp_m, exp_n, exp_s, pi, ws, out);
        fb_k3<<<Kc + 1, 256, 0, stream>>>(exp_m, exp_n, exp_s, bidx, iter_n, out, ws);
        fb_k4<<<1, 64, 0, stream>>>(ws, out);
    }
}